// Round 6
// baseline (28.842 us; speedup 1.0000x reference)
//
#include <hip/hip_runtime.h>

// TransientGenerator — persistent wave-independent gather.
// Grid = B*32 blocks of 256 (= 32 waves/CU exactly, one residency generation).
// No LDS, no barriers: each wave keeps its batch's 256 transients in registers
// (4 per lane), finds the overlapping interval with in-register ballots
// (timings sorted => interval), broadcasts per-transient meta via v_readlane
// (uniform j -> SGPR), and gathers a 1024-sample chunk as 16 samples/lane
// (stride 64: lane-consecutive template loads, 16 independent loads in flight).

constexpr int SR   = 16000;  // SAMPLE_RATE
constexpr int TL   = 1600;   // TRANSIENT_SAMPLES
constexpr int MAXT = 256;    // MAX_TRANSIENTS (== 4 * wave size)
constexpr int CHW  = 1024;   // samples per wave-chunk
constexpr int KPL  = 16;     // samples per lane (CHW / 64)
constexpr int WPB  = 128;    // waves per batch (grid = B * WPB/4 blocks)

__global__ __launch_bounds__(256)
void transient_pw(const float* __restrict__ timings,   // [B,T]
                  const int*   __restrict__ ids,       // [B,T]
                  const float* __restrict__ gains,     // [B,T]
                  const float* __restrict__ templates, // [n_tr,TL]
                  float*       __restrict__ out,       // [B,A]
                  int T, int n_tr, int A, int nchunk)
{
    const int lane = (int)(threadIdx.x & 63);
    const int wg   = blockIdx.x * 4 + (int)(threadIdx.x >> 6);  // global wave id
    const int b    = wg / WPB;
    const int w    = wg % WPB;

    // ---- stage this batch's transients into registers: 4 per lane ----
    int   mx[4];   // (ts clamped to [0,A]) << 8 | clamped id
    float mg[4];   // gain, 0 if invalid (reference 'valid' mask)
#pragma unroll
    for (int q = 0; q < 4; ++q) {
        const int j    = q * 64 + lane;
        const float tm = timings[(size_t)b * T + j];
        const float g  = gains  [(size_t)b * T + j];
        const int   id = ids    [(size_t)b * T + j];
        const int   ts = (int)floorf(tm * (float)SR);   // matches jnp.floor(t*SR) in fp32
        const bool ok  = (g > 0.0f) & (id < n_tr) & (ts < A);
        const int tsc  = min(max(ts, 0), A);            // clamp preserves sorted order
        const int idc  = min(max(id, 0), n_tr - 1);     // reference clips id for gather
        mx[q] = (tsc << 8) | idc;
        mg[q] = ok ? g : 0.0f;
    }

    for (int c = w; c < nchunk; c += WPB) {
        const int chunk0 = c * CHW;

        // ---- overlap interval [lo,hi] via in-register ballots ----
        int lo = T, hi = -1;
#pragma unroll
        for (int q = 0; q < 4; ++q) {
            const int ts  = mx[q] >> 8;
            const bool ov = (ts < chunk0 + CHW) & (ts + TL > chunk0);
            const unsigned long long m = __ballot(ov);
            if (m) {
                lo = min(lo, q * 64 + (int)__builtin_ctzll(m));
                hi = max(hi, q * 64 + 63 - (int)__builtin_clzll(m));
            }
        }

        float acc[KPL];
#pragma unroll
        for (int k = 0; k < KPL; ++k) acc[k] = 0.0f;

        for (int j = lo; j <= hi; ++j) {                 // wave-uniform loop
            const int q = j >> 6, l = j & 63;
            int sx; float sg;
            if (q == 0)      { sx = __builtin_amdgcn_readlane(mx[0], l);
                               sg = __int_as_float(__builtin_amdgcn_readlane(__float_as_int(mg[0]), l)); }
            else if (q == 1) { sx = __builtin_amdgcn_readlane(mx[1], l);
                               sg = __int_as_float(__builtin_amdgcn_readlane(__float_as_int(mg[1]), l)); }
            else if (q == 2) { sx = __builtin_amdgcn_readlane(mx[2], l);
                               sg = __int_as_float(__builtin_amdgcn_readlane(__float_as_int(mg[2]), l)); }
            else             { sx = __builtin_amdgcn_readlane(mx[3], l);
                               sg = __int_as_float(__builtin_amdgcn_readlane(__float_as_int(mg[3]), l)); }
            if (sg == 0.0f) continue;                    // uniform skip of masked transients

            const int ts = sx >> 8;
            const float* __restrict__ row = templates + (size_t)(sx & 255) * TL;
            const int off0 = chunk0 + lane - ts;         // this lane's k=0 template offset

            if (ts <= chunk0 && ts + TL >= chunk0 + CHW) {
                // interior: all 16 offsets in [0,TL) for every lane — no masks,
                // 16 independent loads off one base (imm offsets 0..3840B)
#pragma unroll
                for (int k = 0; k < KPL; ++k)
                    acc[k] = fmaf(sg, row[off0 + k * 64], acc[k]);
            } else {
                // boundary: clamp address, zero gain out of range
#pragma unroll
                for (int k = 0; k < KPL; ++k) {
                    const int o  = off0 + k * 64;
                    const int oc = min(max(o, 0), TL - 1);
                    const float gm = ((unsigned)o < (unsigned)TL) ? sg : 0.0f;
                    acc[k] = fmaf(gm, row[oc], acc[k]);
                }
            }
        }

        // ---- store: 16 lane-consecutive dword stores (every element exactly once) ----
        float* ob = out + (size_t)b * A + chunk0 + lane;
#pragma unroll
        for (int k = 0; k < KPL; ++k) {
            if (chunk0 + k * 64 + lane < A) ob[k * 64] = acc[k];
        }
    }
}

extern "C" void kernel_launch(void* const* d_in, const int* in_sizes, int n_in,
                              void* d_out, int out_size, void* d_ws, size_t ws_size,
                              hipStream_t stream) {
    const float* timings   = (const float*)d_in[0];
    const int*   ids       = (const int*)  d_in[1];
    const float* gains     = (const float*)d_in[2];
    const float* templates = (const float*)d_in[3];
    float*       out       = (float*)d_out;

    const int T      = MAXT;               // reference MAX_TRANSIENTS
    const int B      = in_sizes[0] / T;
    const int n_tr   = in_sizes[3] / TL;   // templates are [n_tr, TL]
    const int A      = out_size / B;       // audio_length
    const int nchunk = (A + CHW - 1) / CHW;

    dim3 grid(B * (WPB / 4)), block(256);  // 4 waves per block
    transient_pw<<<grid, block, 0, stream>>>(timings, ids, gains, templates, out,
                                             T, n_tr, A, nchunk);
}

// Round 7
// 24.980 us; speedup vs baseline: 1.1546x; 1.1546x over previous
//
#include <hip/hip_runtime.h>

// TransientGenerator, gather with stride-64 lane mapping (R5 structure)
// + NON-TEMPORAL output stores: the 41 MB output stream was evicting the
// 128 KB template set from each XCD's 4 MB L2 (evidence: R4's FETCH_SIZE
// = 1157 MB >> total input bytes), forcing every template slice to refetch
// from Infinity Cache. NT stores keep L2 clean -> template reads stay L2-hit.

constexpr int SR    = 16000;  // SAMPLE_RATE
constexpr int TL    = 1600;   // TRANSIENT_SAMPLES
constexpr int MAXT  = 256;    // MAX_TRANSIENTS (== blockDim)
constexpr int NTHR  = 256;
constexpr int CHUNK = 1024;   // NTHR * 4 samples per block

__global__ __launch_bounds__(NTHR)
void transient_gather(const float* __restrict__ timings,   // [B,T]
                      const int*   __restrict__ ids,       // [B,T]
                      const float* __restrict__ gains,     // [B,T]
                      const float* __restrict__ templates, // [n_tr,TL]
                      float*       __restrict__ out,       // [B,A]
                      int T, int n_tr, int A)
{
    __shared__ int2               s_m[MAXT];   // .x = (ts<<8)|id (clamped), .y = gain bits (0 if invalid)
    __shared__ unsigned long long s_mask[NTHR / 64];

    const int b      = blockIdx.y;
    const int chunk0 = blockIdx.x * CHUNK;
    const int tid    = (int)threadIdx.x;

    // Stage transient j = tid (T == NTHR) and test window overlap.
    {
        const float tm = timings[(size_t)b * T + tid];
        const float g  = gains  [(size_t)b * T + tid];
        const int   id = ids    [(size_t)b * T + tid];
        const int   ts = (int)floorf(tm * (float)SR);   // matches jnp.floor(t*SR) in fp32
        const bool ok  = (g > 0.0f) & (id < n_tr) & (ts < A);
        const int tsc  = min(max(ts, 0), A);            // clamp preserves sorted order
        const int idc  = min(max(id, 0), n_tr - 1);
        s_m[tid] = make_int2((tsc << 8) | idc, ok ? __float_as_int(g) : 0);

        // overlap iff ts < chunk_end && ts + TL > chunk0  (interval in sorted ts)
        const bool ov = (tsc < chunk0 + CHUNK) && (tsc + TL > chunk0);
        const unsigned long long m = __ballot(ov);
        if ((tid & 63) == 0) s_mask[tid >> 6] = m;
    }
    __syncthreads();

    int lo = T, hi = -1;
#pragma unroll
    for (int w = 0; w < NTHR / 64; ++w) {
        const unsigned long long mw = s_mask[w];
        if (mw) {
            lo = min(lo, w * 64 + (int)__builtin_ctzll(mw));
            hi = max(hi, w * 64 + 63 - (int)__builtin_clzll(mw));
        }
    }

    float acc[4] = {0.f, 0.f, 0.f, 0.f};
    const int off_base = chunk0 + tid;                  // sample index of k=0

    for (int j = lo; j <= hi; ++j) {                    // known trip count, no break
        const int2  m  = s_m[j];                        // uniform -> broadcast ds_read_b64
        const int   ts = m.x >> 8;
        const float g  = __int_as_float(m.y);
        const float* __restrict__ row = templates + (size_t)(m.x & 255) * TL;
        const int off0 = off_base - ts;
#pragma unroll
        for (int k = 0; k < 4; ++k) {
            const int o = off0 + k * NTHR;
            if ((unsigned)o < (unsigned)TL)             // exec-masked, lane-consecutive load
                acc[k] += g * row[o];
        }
    }

    // Non-temporal stores: stream the output past L2 so templates stay resident.
    float* ob = out + (size_t)b * A + off_base;
#pragma unroll
    for (int k = 0; k < 4; ++k) {
        if (off_base + k * NTHR < A)
            __builtin_nontemporal_store(acc[k], &ob[k * NTHR]);   // coalesced dword store, NT
    }
}

extern "C" void kernel_launch(void* const* d_in, const int* in_sizes, int n_in,
                              void* d_out, int out_size, void* d_ws, size_t ws_size,
                              hipStream_t stream) {
    const float* timings   = (const float*)d_in[0];
    const int*   ids       = (const int*)  d_in[1];
    const float* gains     = (const float*)d_in[2];
    const float* templates = (const float*)d_in[3];
    float*       out       = (float*)d_out;

    const int T    = MAXT;                 // reference MAX_TRANSIENTS
    const int B    = in_sizes[0] / T;
    const int n_tr = in_sizes[3] / TL;     // templates are [n_tr, TL]
    const int A    = out_size / B;         // audio_length

    dim3 grid((A + CHUNK - 1) / CHUNK, B), block(NTHR);
    transient_gather<<<grid, block, 0, stream>>>(timings, ids, gains, templates, out,
                                                 T, n_tr, A);
}